// Round 9
// baseline (728.161 us; speedup 1.0000x reference)
//
#include <hip/hip_runtime.h>
#include <stdint.h>

typedef __attribute__((ext_vector_type(8))) short short8;
typedef __attribute__((ext_vector_type(4))) short sh4;
typedef __attribute__((ext_vector_type(4))) float f32x4;

__device__ __forceinline__ float bf2f(unsigned short u) {
  union { unsigned int i; float f; } v; v.i = ((unsigned int)u) << 16; return v.f;
}
__device__ __forceinline__ unsigned short f2bf(float f) {
  union { float f; unsigned int i; } v; v.f = f;
  unsigned int u = v.i;
  return (unsigned short)((u + 0x7fffu + ((u >> 16) & 1u)) >> 16);
}

#define B_SZ 2
#define T_SEQ 2048
#define NH 16
#define DH 128
#define ROPE_R 32
#define SCALE_Q 0.08838834764831845f

// Load 8 consecutive elements as bf16 fragment; F=true -> source is fp32.
template <bool F>
__device__ __forceinline__ short8 ld8(const void* base, size_t idx) {
  if constexpr (F) {
    const float* p = (const float*)base + idx;
    f32x4 a = *(const f32x4*)p;
    f32x4 b = *(const f32x4*)(p + 4);
    short8 r;
    r[0] = (short)f2bf(a[0]); r[1] = (short)f2bf(a[1]);
    r[2] = (short)f2bf(a[2]); r[3] = (short)f2bf(a[3]);
    r[4] = (short)f2bf(b[0]); r[5] = (short)f2bf(b[1]);
    r[6] = (short)f2bf(b[2]); r[7] = (short)f2bf(b[3]);
    return r;
  } else {
    return *(const short8*)((const unsigned short*)base + idx);
  }
}

// ---------------------------------------------------------------------------
// Fallback GEMM (previous session's proven kernel). Used only if workspace is
// too small for the bf16-converted-operand fast path.
// ---------------------------------------------------------------------------
template <bool AF, bool BF, bool C32>
__global__ __launch_bounds__(256) void gemm_bt(
    const void* __restrict__ Ap, const void* __restrict__ Bp,
    void* __restrict__ Cp, int M, int N, int K) {
  __shared__ unsigned short Al[128][40];
  __shared__ unsigned short Bl[128][40];
  const int tid = threadIdx.x;
  const int lane = tid & 63, w = tid >> 6;
  const int wm = w >> 1, wn = w & 1;
  const int quad = lane >> 4, l16 = lane & 15;
  const int m0 = blockIdx.y * 128, n0 = blockIdx.x * 128;
  f32x4 acc[4][4];
#pragma unroll
  for (int i = 0; i < 4; ++i)
#pragma unroll
    for (int j = 0; j < 4; ++j)
#pragma unroll
      for (int r = 0; r < 4; ++r) acc[i][j][r] = 0.f;

  for (int k0 = 0; k0 < K; k0 += 32) {
    __syncthreads();
#pragma unroll
    for (int p = 0; p < 2; ++p) {
      int v = tid + p * 256;
      int row = v >> 2, kc = (v & 3) * 8;
      *(short8*)&Al[row][kc] = ld8<AF>(Ap, (size_t)(m0 + row) * K + k0 + kc);
      *(short8*)&Bl[row][kc] = ld8<BF>(Bp, (size_t)(n0 + row) * K + k0 + kc);
    }
    __syncthreads();
    short8 a[4];
#pragma unroll
    for (int i = 0; i < 4; ++i)
      a[i] = *(const short8*)&Al[wm * 64 + i * 16 + l16][quad * 8];
#pragma unroll
    for (int j = 0; j < 4; ++j) {
      short8 b = *(const short8*)&Bl[wn * 64 + j * 16 + l16][quad * 8];
#pragma unroll
      for (int i = 0; i < 4; ++i)
        acc[i][j] = __builtin_amdgcn_mfma_f32_16x16x32_bf16(a[i], b, acc[i][j], 0, 0, 0);
    }
  }
#pragma unroll
  for (int i = 0; i < 4; ++i)
#pragma unroll
    for (int j = 0; j < 4; ++j) {
      int row = m0 + wm * 64 + i * 16 + quad * 4;
      int col = n0 + wn * 64 + j * 16 + l16;
#pragma unroll
      for (int r = 0; r < 4; ++r) {
        if constexpr (C32)
          ((float*)Cp)[(size_t)(row + r) * N + col] = acc[i][j][r];
        else
          ((unsigned short*)Cp)[(size_t)(row + r) * N + col] = f2bf(acc[i][j][r]);
      }
    }
}

// ---------------------------------------------------------------------------
// Fast GEMM: m97 structure. Both operands bf16 in global memory; staging via
// global_load_lds dwordx4 (direct HBM->LDS DMA, no VGPR round trip, no
// per-element convert). Linear LDS [rows][32] (gload_lds needs linear dest).
// ---------------------------------------------------------------------------
__device__ __forceinline__ void gload_lds16(const unsigned short* g, unsigned short* l) {
  __builtin_amdgcn_global_load_lds(
      (const __attribute__((address_space(1))) void*)g,
      (__attribute__((address_space(3))) void*)l, 16, 0, 0);
}

template <int BN, bool C32>
__global__ __launch_bounds__(256) void gemm_lds(
    const unsigned short* __restrict__ A, const unsigned short* __restrict__ Bw,
    void* __restrict__ Cp, int M, int N, int K) {
  __shared__ unsigned short Al[128][32];
  __shared__ unsigned short Bl[BN][32];
  const int tid = threadIdx.x;
  const int lane = tid & 63, w = tid >> 6;
  const int wm = w >> 1, wn = w & 1;
  const int quad = lane >> 4, l16 = lane & 15;
  const int m0 = blockIdx.y * 128, n0 = blockIdx.x * BN;
  constexpr int NJ = BN / 32;
  f32x4 acc[4][NJ];
#pragma unroll
  for (int i = 0; i < 4; ++i)
#pragma unroll
    for (int j = 0; j < NJ; ++j)
#pragma unroll
      for (int r = 0; r < 4; ++r) acc[i][j][r] = 0.f;

  for (int k0 = 0; k0 < K; k0 += 32) {
    __syncthreads();
#pragma unroll
    for (int p = 0; p < 2; ++p) {
      int c = w * 128 + p * 64 + lane;
      gload_lds16(A + (size_t)(m0 + (c >> 2)) * K + k0 + (c & 3) * 8,
                  &Al[0][0] + (size_t)(w * 128 + p * 64) * 8);
    }
#pragma unroll
    for (int p = 0; p < BN / 64; ++p) {
      int c = w * BN + p * 64 + lane;
      gload_lds16(Bw + (size_t)(n0 + (c >> 2)) * K + k0 + (c & 3) * 8,
                  &Bl[0][0] + (size_t)(w * BN + p * 64) * 8);
    }
    __syncthreads();
    short8 a[4], b[NJ];
#pragma unroll
    for (int i = 0; i < 4; ++i)
      a[i] = *(const short8*)&Al[wm * 64 + i * 16 + l16][quad * 8];
#pragma unroll
    for (int j = 0; j < NJ; ++j)
      b[j] = *(const short8*)&Bl[wn * (BN / 2) + j * 16 + l16][quad * 8];
#pragma unroll
    for (int j = 0; j < NJ; ++j)
#pragma unroll
      for (int i = 0; i < 4; ++i)
        acc[i][j] = __builtin_amdgcn_mfma_f32_16x16x32_bf16(a[i], b[j], acc[i][j], 0, 0, 0);
  }
#pragma unroll
  for (int i = 0; i < 4; ++i)
#pragma unroll
    for (int j = 0; j < NJ; ++j) {
      int row = m0 + wm * 64 + i * 16 + quad * 4;
      int col = n0 + wn * (BN / 2) + j * 16 + l16;
#pragma unroll
      for (int r = 0; r < 4; ++r) {
        if constexpr (C32)
          ((float*)Cp)[(size_t)(row + r) * N + col] = acc[i][j][r];
        else
          ((unsigned short*)Cp)[(size_t)(row + r) * N + col] = f2bf(acc[i][j][r]);
      }
    }
}

// ---------------------------------------------------------------------------
// One-shot fp32 -> bf16 conversion of x + all weights (8 segments, 1 launch).
// ---------------------------------------------------------------------------
struct CvtArgs {
  const float* src[8];
  unsigned short* dst[8];
  long long n4[8];
};

__global__ __launch_bounds__(256) void cvt_multi(CvtArgs a, long long total4) {
  for (long long g = (long long)blockIdx.x * 256 + threadIdx.x; g < total4;
       g += (long long)gridDim.x * 256) {
    long long r = g;
    int s = 0;
    while (r >= a.n4[s]) { r -= a.n4[s]; ++s; }
    f32x4 v = ((const f32x4*)a.src[s])[r];
    sh4 o;
    o[0] = (short)f2bf(v[0]); o[1] = (short)f2bf(v[1]);
    o[2] = (short)f2bf(v[2]); o[3] = (short)f2bf(v[3]);
    ((sh4*)a.dst[s])[r] = o;
  }
}

// ---------------------------------------------------------------------------
__global__ __launch_bounds__(256) void rms_norm_ip(
    unsigned short* __restrict__ x, const float* __restrict__ w, int N) {
  unsigned short* row = x + (size_t)blockIdx.x * N;
  float vals[8];
  int cnt = 0;
  float ss = 0.f;
  for (int j = threadIdx.x; j < N; j += 256) {
    float v = bf2f(row[j]);
    vals[cnt++] = v;
    ss += v * v;
  }
#pragma unroll
  for (int d = 1; d < 64; d <<= 1) ss += __shfl_xor(ss, d);
  __shared__ float ws4[4];
  if ((threadIdx.x & 63) == 0) ws4[threadIdx.x >> 6] = ss;
  __syncthreads();
  float tot = ws4[0] + ws4[1] + ws4[2] + ws4[3];
  float scale = rsqrtf(tot / (float)N + 1e-6f);
  cnt = 0;
  for (int j = threadIdx.x; j < N; j += 256)
    row[j] = f2bf(w[j] * vals[cnt++] * scale);
}

// ---------------------------------------------------------------------------
__global__ __launch_bounds__(256) void prep_qk(
    const unsigned short* __restrict__ q_all, const unsigned short* __restrict__ k_all,
    const float* __restrict__ cosb, const float* __restrict__ sinb,
    unsigned short* __restrict__ Q, unsigned short* __restrict__ K) {
  const int bt = blockIdx.x;
  const int b = bt >> 11, t = bt & (T_SEQ - 1);
  const unsigned short* qr = q_all + (size_t)bt * (NH * DH);
  const unsigned short* kr = k_all + (size_t)bt * (NH * DH);
  for (int d = threadIdx.x; d < NH * DH; d += 256) {
    int h = d >> 7, dd = d & 127;
    float qv = bf2f(qr[d]);
    float kv = bf2f(kr[d]);
    if (dd < ROPE_R) {
      float c = cosb[t * ROPE_R + dd];
      float s = sinb[t * ROPE_R + dd];
      float qrot = (dd < 16) ? -bf2f(qr[d + 16]) : bf2f(qr[d - 16]);
      float krot = (dd < 16) ? -bf2f(kr[d + 16]) : bf2f(kr[d - 16]);
      qv = qv * c + qrot * s;
      kv = kv * c + krot * s;
    }
    size_t o = ((size_t)(b * NH + h) * T_SEQ + t) * DH + dd;
    Q[o] = f2bf(qv * SCALE_Q);
    K[o] = f2bf(kv);
  }
}

// ---------------------------------------------------------------------------
__global__ __launch_bounds__(256) void prep_vt(
    const unsigned short* __restrict__ v_all, const unsigned short* __restrict__ gates,
    unsigned short* __restrict__ Vt) {
  __shared__ unsigned short tile[64][130];
  const int bh = blockIdx.y, b = bh >> 4, h = bh & 15;
  const int t0 = blockIdx.x * 64;
  for (int idx = threadIdx.x; idx < 64 * 128; idx += 256) {
    int tt = idx >> 7, dd = idx & 127;
    size_t rowbase = (size_t)(b * T_SEQ + t0 + tt);
    float v = bf2f(v_all[rowbase * (NH * DH) + h * DH + dd]);
    float g = bf2f(gates[rowbase * (NH * DH) + h * DH + dd]);
    float sg = g / (1.f + __expf(-g));
    tile[tt][dd] = f2bf(v * sg);
  }
  __syncthreads();
  for (int idx = threadIdx.x; idx < 64 * 128; idx += 256) {
    int dd = idx >> 6, tt = idx & 63;
    Vt[((size_t)bh * DH + dd) * T_SEQ + t0 + tt] = tile[tt][dd];
  }
}

// ---------------------------------------------------------------------------
// SWAPPED-QK online-softmax update (m214-style, 16x16 form).
// sc = mfma(K-frag, Q-frag): C[row=key, col=q] -> lane (l16,quad) holds P^T
// values for ONE q (=l16): keys k = jt*16 + quad*4 + r. Softmax is per-lane
// scalar (m_run, l_part). P -> PV B-fragment via in-register quad-swap
// shuffles (no LDS round trip):
//   target (l16,quad) needs P[k=kk*32+quad*8+j][q=l16];
//   source element: reg (jt=kk*2+(quad>>1), r=j&3),
//   source lane: quad_s=(quad&1)*2 (+1 for j>=4), same l16.
// PV: O^T = mfma(V^T-frag as A, P-frag as B): C[row=d, col=q].
// All K/V/Q load patterns identical to the proven unswapped kernel (A- and
// B-fragments share the same lane layout in this MFMA family).
// ---------------------------------------------------------------------------
__device__ __forceinline__ void attn_update(
    const unsigned short (*Kl)[132], const unsigned short (*Vl)[68],
    const short8* qf, int qrow, int kb, bool diag,
    int quad, int l16, f32x4* O, float& m_run, float& l_part) {
  f32x4 sc[4];
  __builtin_amdgcn_s_setprio(1);
#pragma unroll
  for (int jt = 0; jt < 4; ++jt) {
#pragma unroll
    for (int r = 0; r < 4; ++r) sc[jt][r] = 0.f;
#pragma unroll
    for (int kk = 0; kk < 4; ++kk) {
      short8 kf = *(const short8*)&Kl[jt * 16 + l16][kk * 32 + quad * 8];
      sc[jt] = __builtin_amdgcn_mfma_f32_16x16x32_bf16(kf, qf[kk], sc[jt], 0, 0, 0);
    }
  }
  __builtin_amdgcn_s_setprio(0);
  if (diag) {
#pragma unroll
    for (int jt = 0; jt < 4; ++jt)
#pragma unroll
      for (int r = 0; r < 4; ++r) {
        int key = kb + jt * 16 + quad * 4 + r;
        if (key > qrow) sc[jt][r] = -1e30f;
      }
  }
  // per-lane max over this lane's 16 keys (all for q = l16)
  f32x4 t4 = sc[0];
#pragma unroll
  for (int jt = 1; jt < 4; ++jt)
#pragma unroll
    for (int r = 0; r < 4; ++r) t4[r] = fmaxf(t4[r], sc[jt][r]);
  float pmax = fmaxf(fmaxf(t4[0], t4[1]), fmaxf(t4[2], t4[3]));
  bool near = pmax <= m_run + 8.f;
  if (!__all((int)near)) {
    // slow path (rare): cross-quad max (xor 16/32 swap quad bits), rescale
    float mx = pmax;
    mx = fmaxf(mx, __shfl_xor(mx, 16));
    mx = fmaxf(mx, __shfl_xor(mx, 32));
    float mnew = fmaxf(m_run, mx);
    float alpha = __expf(m_run - mnew);
    m_run = mnew;
    l_part *= alpha;
#pragma unroll
    for (int jn = 0; jn < 8; ++jn)
#pragma unroll
      for (int r = 0; r < 4; ++r) O[jn][r] *= alpha;
  }
  // exp + per-lane partial sum (true row sum = epilogue cross-quad reduce)
#pragma unroll
  for (int jt = 0; jt < 4; ++jt)
#pragma unroll
    for (int r = 0; r < 4; ++r) {
      float p = __expf(sc[jt][r] - m_run);
      sc[jt][r] = p;
      l_part += p;
    }
  // pack bf16 pairs (r even, r odd) -> u32; shuffle quad-swap into B-frags
  unsigned int pk[4][2];
#pragma unroll
  for (int jt = 0; jt < 4; ++jt)
#pragma unroll
    for (int i = 0; i < 2; ++i)
      pk[jt][i] = (unsigned int)f2bf(sc[jt][2 * i]) |
                  ((unsigned int)f2bf(sc[jt][2 * i + 1]) << 16);
  const int srcA = ((quad & 1) * 2) * 16 + l16;
  const int srcB = srcA + 16;
  const bool hisel = quad >= 2;  // jt = kk*2 + (quad>>1)
  union { short8 s; unsigned int u[4]; } pb[2];
#pragma unroll
  for (int kk = 0; kk < 2; ++kk) {
#pragma unroll
    for (int i = 0; i < 2; ++i) {
      unsigned int a0 = __shfl(pk[kk * 2][i], srcA);
      unsigned int a1 = __shfl(pk[kk * 2 + 1][i], srcA);
      pb[kk].u[i] = hisel ? a1 : a0;  // j = 2i, 2i+1
      unsigned int b0 = __shfl(pk[kk * 2][i], srcB);
      unsigned int b1 = __shfl(pk[kk * 2 + 1][i], srcB);
      pb[kk].u[2 + i] = hisel ? b1 : b0;  // j = 4+2i, 5+2i
    }
  }
  __builtin_amdgcn_s_setprio(1);
#pragma unroll
  for (int jn = 0; jn < 8; ++jn) {
#pragma unroll
    for (int kk = 0; kk < 2; ++kk) {
      short8 vf = *(const short8*)&Vl[jn * 16 + l16][kk * 32 + quad * 8];
      O[jn] = __builtin_amdgcn_mfma_f32_16x16x32_bf16(vf, pb[kk].s, O[jn], 0, 0, 0);
    }
  }
  __builtin_amdgcn_s_setprio(0);
}

// ---------------------------------------------------------------------------
// Causal flash attention: round-7 shell (LDS K/V staging, 8-wave A/B tile
// split, paired qa/qb blocks, XCD swizzle) + swapped-QK in-register softmax
// (P LDS round-trip eliminated; softmax per-lane scalar). LDS 34.2 KB.
// Q,K: (B,H,T,128) (Q pre-scaled); Vt: (B,H,128,T). Out: (B,T,H*128) bf16.
// Grid: 512 blocks; bh = (l&7) + 8*((l>>3)>>4) keeps each bh on one XCD.
// ---------------------------------------------------------------------------
__global__ __launch_bounds__(512, 2) void flash_attn(
    const unsigned short* __restrict__ Q, const unsigned short* __restrict__ K,
    const unsigned short* __restrict__ Vt, unsigned short* __restrict__ Out) {
  __shared__ unsigned short Kl[64][132];
  __shared__ unsigned short Vl[128][68];
  const int l = blockIdx.x;
  const int s = l & 7, qq = l >> 3;
  const int bh = s + 8 * (qq >> 4);
  const int qp = qq & 15;
  const int qa = qp, qb = 31 - qp;
  const int b = bh >> 4, h = bh & 15;
  const int tid = threadIdx.x;
  const int lane = tid & 63, w = tid >> 6;  // w in 0..7
  const int wt = w & 3;                     // 16-row quarter within the tile
  const bool isB = w >= 4;                  // tile ownership
  const int myq = isB ? qb : qa;
  const int quad = lane >> 4, l16 = lane & 15;
  const unsigned short* Qb = Q + (size_t)bh * T_SEQ * DH;
  const unsigned short* Kb = K + (size_t)bh * T_SEQ * DH;
  const unsigned short* Vb = Vt + (size_t)bh * DH * T_SEQ;

  short8 qf[4];
  const int qrow = myq * 64 + wt * 16 + l16;  // this lane's q row (one per lane)
#pragma unroll
  for (int kk = 0; kk < 4; ++kk)
    qf[kk] = *(const short8*)&Qb[(size_t)qrow * DH + kk * 32 + quad * 8];

  f32x4 O[8];
  float m_run = -1e30f, l_part = 0.f;
#pragma unroll
  for (int jn = 0; jn < 8; ++jn)
#pragma unroll
    for (int r = 0; r < 4; ++r) O[jn][r] = 0.f;

  // staging: 512 threads x 2 coalesced 16B chunks each for K (64x128) and
  // V (128x64)
  short8 krg[2], vrg[2];
#pragma unroll
  for (int p = 0; p < 2; ++p) {
    int id = tid + p * 512;
    krg[p] = *(const short8*)&Kb[(size_t)(id >> 4) * DH + (id & 15) * 8];
    vrg[p] = *(const short8*)&Vb[(size_t)(id >> 3) * T_SEQ + (id & 7) * 8];
  }
#pragma unroll
  for (int p = 0; p < 2; ++p) {
    int id = tid + p * 512;
    *(short8*)&Kl[id >> 4][(id & 15) * 8] = krg[p];
    *(short8*)&Vl[id >> 3][(id & 7) * 8] = vrg[p];
  }
  __syncthreads();

  const int last = qb;
  for (int kt = 0; kt <= last; ++kt) {
    const int kb = kt * 64;
    if (kt < last) {  // prefetch next tile into registers (overlaps compute)
      const int nb = kb + 64;
#pragma unroll
      for (int p = 0; p < 2; ++p) {
        int id = tid + p * 512;
        krg[p] = *(const short8*)&Kb[(size_t)(nb + (id >> 4)) * DH + (id & 15) * 8];
        vrg[p] = *(const short8*)&Vb[(size_t)(id >> 3) * T_SEQ + nb + (id & 7) * 8];
      }
    }
    if (isB || kt <= qa)
      attn_update(Kl, Vl, qf, qrow, kb, kt == (isB ? last : qa),
                  quad, l16, O, m_run, l_part);
    if (kt < last) {
      __syncthreads();  // all waves done reading Kl/Vl
#pragma unroll
      for (int p = 0; p < 2; ++p) {
        int id = tid + p * 512;
        *(short8*)&Kl[id >> 4][(id & 15) * 8] = krg[p];
        *(short8*)&Vl[id >> 3][(id & 7) * 8] = vrg[p];
      }
      __syncthreads();  // staging visible
    }
  }

  // epilogue: true row sum = cross-quad reduce (xor 16/32 swap quad bits)
  float lsum = l_part;
  lsum += __shfl_xor(lsum, 16);
  lsum += __shfl_xor(lsum, 32);
  const float inv = 1.f / lsum;
  // O^T layout: O[jn][r] = Out[d = jn*16+quad*4+r][q = l16] -> packed stores
#pragma unroll
  for (int jn = 0; jn < 8; ++jn) {
    sh4 o4;
#pragma unroll
    for (int r = 0; r < 4; ++r) o4[r] = (short)f2bf(O[jn][r] * inv);
    *(sh4*)&Out[((size_t)(b * T_SEQ) + qrow) * (NH * DH) + h * DH + jn * 16 + quad * 4] = o4;
  }
}

// ---------------------------------------------------------------------------
// Workspace plan. Base 74 MiB:
//   R0 [0,6.29M): qs -> later omid ; R1: kvs ; R2: gates -> k_all ;
//   R3: v_all -> Qb ; R4: Vt ; R5: Kb
// Fast path appends (needs ws_size >= ~114 MiB):
//   xb @77,594,624 (16.78M) ; bf16 weights @94,371,840 (25.17M)
// ---------------------------------------------------------------------------
extern "C" void kernel_launch(void* const* d_in, const int* in_sizes, int n_in,
                              void* d_out, int out_size, void* d_ws, size_t ws_size,
                              hipStream_t stream) {
  const void*  x     = d_in[0];
  const float* cosb  = (const float*)d_in[1];
  const float* sinb  = (const float*)d_in[2];
  const void*  Wq_s  = d_in[3];
  const float* qs_w  = (const float*)d_in[4];
  const void*  Wkv_s = d_in[5];
  const float* kvs_w = (const float*)d_in[6];
  const void*  Wq_p  = d_in[7];
  const float* Wkv_p = (const float*)d_in[8];
  const void*  Wg_p  = d_in[9];
  const void*  Wo_p  = d_in[10];
  const float* o_w   = (const float*)d_in[11];
  const void*  Wo_s  = d_in[12];
  (void)in_sizes; (void)n_in; (void)out_size;

  const int M = B_SZ * T_SEQ;  // 4096
  char* ws = (char*)d_ws;
  unsigned short* qs    = (unsigned short*)(ws + 0);
  unsigned short* omid  = qs;
  unsigned short* kvs   = (unsigned short*)(ws + 6291456);
  unsigned short* gates = (unsigned short*)(ws + 10485760);
  unsigned short* k_all = gates;
  unsigned short* v_all = (unsigned short*)(ws + 27262976);
  unsigned short* Qb    = v_all;
  unsigned short* Vt    = (unsigned short*)(ws + 44040192);
  unsigned short* Kb    = (unsigned short*)(ws + 60817408);
  unsigned short* q_all = (unsigned short*)d_out;
  unsigned short* attn  = (unsigned short*)d_out;

  dim3 blk(256);
  dim3 blk512(512);
  const size_t FAST_WS_NEEDED = 119537664;  // 114 MiB

  if (ws_size >= FAST_WS_NEEDED) {
    unsigned short* xb     = (unsigned short*)(ws + 77594624);
    unsigned short* Wq_s_b = (unsigned short*)(ws + 94371840);
    unsigned short* Wkv_s_b= (unsigned short*)(ws + 97517568);
    unsigned short* Wg_p_b = (unsigned short*)(ws + 99614720);
    unsigned short* Wq_p_b = (unsigned short*)(ws + 108003328);
    unsigned short* Wkv_p_b= (unsigned short*)(ws + 111149056);
    unsigned short* Wo_p_b = (unsigned short*)(ws + 115343360);
    unsigned short* Wo_s_b = (unsigned short*)(ws + 117440512);

    CvtArgs ca;
    ca.src[0] = (const float*)x;    ca.dst[0] = xb;      ca.n4[0] = 2097152;
    ca.src[1] = (const float*)Wq_s; ca.dst[1] = Wq_s_b;  ca.n4[1] = 393216;
    ca.src[2] = (const float*)Wkv_s;ca.dst[2] = Wkv_s_b; ca.n4[2] = 262144;
    ca.src[3] = (const float*)Wg_p; ca.dst[3] = Wg_p_b;  ca.n4[3] = 1048576;
    ca.src[4] = (const float*)Wq_p; ca.dst[4] = Wq_p_b;  ca.n4[4] = 393216;
    ca.src[5] = Wkv_p;              ca.dst[5] = Wkv_p_b; ca.n4[5] = 524288;
    ca.src[6] = (const float*)Wo_p; ca.dst[6] = Wo_p_b;  ca.n4[6] = 262144;
    ca.src[7] = (const float*)Wo_s; ca.dst[7] = Wo_s_b;  ca.n4[7] = 262144;
    long long total4 = 5242880;
    cvt_multi<<<dim3(2048), blk, 0, stream>>>(ca, total4);

    gemm_lds<128, false><<<dim3(768 / 128, M / 128), blk, 0, stream>>>(xb, Wq_s_b, qs, M, 768, 2048);
    gemm_lds<64,  false><<<dim3(512 / 64,  M / 128), blk, 0, stream>>>(xb, Wkv_s_b, kvs, M, 512, 2048);
    gemm_lds<128, false><<<dim3(2048 / 128, M / 128), blk, 0, stream>>>(xb, Wg_p_b, gates, M, 2048, 2048);
    rms_norm_ip<<<M, blk, 0, stream>>>(qs, qs_w, 768);
    rms_norm_ip<<<M, blk, 0, stream>>>(kvs, kvs_w, 512);
    gemm_lds<128, false><<<dim3(2048 / 128, M / 128), blk, 0, stream>>>(qs, Wq_p_b, q_all, M, 2048, 768);
    gemm_lds<128, false><<<dim3(2048 / 128, M / 128), blk, 0, stream>>>(
        kvs, Wkv_p_b + (size_t)2048 * 512, v_all, M, 2048, 512);
    prep_vt<<<dim3(T_SEQ / 64, B_SZ * NH), blk, 0, stream>>>(v_all, gates, Vt);
    gemm_lds<128, false><<<dim3(2048 / 128, M / 128), blk, 0, stream>>>(kvs, Wkv_p_b, k_all, M, 2048, 512);
    prep_qk<<<M, blk, 0, stream>>>(q_all, k_all, cosb, sinb, Qb, Kb);
    flash_attn<<<dim3(512), blk512, 0, stream>>>(Qb, Kb, Vt, attn);
    gemm_lds<64,  false><<<dim3(512 / 64, M / 128), blk, 0, stream>>>(attn, Wo_p_b, omid, M, 512, 2048);
    rms_norm_ip<<<M, blk, 0, stream>>>(omid, o_w, 512);
    gemm_lds<128, true><<<dim3(2048 / 128, M / 128), blk, 0, stream>>>(omid, Wo_s_b, d_out, M, 2048, 512);
  } else {
    gemm_bt<true, true, false><<<dim3(768 / 128, M / 128), blk, 0, stream>>>(x, Wq_s, qs, M, 768, 2048);
    gemm_bt<true, true, false><<<dim3(512 / 128, M / 128), blk, 0, stream>>>(x, Wkv_s, kvs, M, 512, 2048);
    gemm_bt<true, true, false><<<dim3(2048 / 128, M / 128), blk, 0, stream>>>(x, Wg_p, gates, M, 2048, 2048);
    rms_norm_ip<<<M, blk, 0, stream>>>(qs, qs_w, 768);
    rms_norm_ip<<<M, blk, 0, stream>>>(kvs, kvs_w, 512);
    gemm_bt<false, true, false><<<dim3(2048 / 128, M / 128), blk, 0, stream>>>(qs, Wq_p, q_all, M, 2048, 768);
    gemm_bt<false, true, false><<<dim3(2048 / 128, M / 128), blk, 0, stream>>>(
        kvs, Wkv_p + (size_t)2048 * 512, v_all, M, 2048, 512);
    prep_vt<<<dim3(T_SEQ / 64, B_SZ * NH), blk, 0, stream>>>(v_all, gates, Vt);
    gemm_bt<false, true, false><<<dim3(2048 / 128, M / 128), blk, 0, stream>>>(kvs, Wkv_p, k_all, M, 2048, 512);
    prep_qk<<<M, blk, 0, stream>>>(q_all, k_all, cosb, sinb, Qb, Kb);
    flash_attn<<<dim3(512), blk512, 0, stream>>>(Qb, Kb, Vt, attn);
    gemm_bt<false, true, false><<<dim3(512 / 128, M / 128), blk, 0, stream>>>(attn, Wo_p, omid, M, 512, 2048);
    rms_norm_ip<<<M, blk, 0, stream>>>(omid, o_w, 512);
    gemm_bt<false, true, true><<<dim3(2048 / 128, M / 128), blk, 0, stream>>>(omid, Wo_s, d_out, M, 2048, 512);
  }
}

// Round 10
// 668.400 us; speedup vs baseline: 1.0894x; 1.0894x over previous
//
#include <hip/hip_runtime.h>
#include <stdint.h>

typedef __attribute__((ext_vector_type(8))) short short8;
typedef __attribute__((ext_vector_type(4))) short sh4;
typedef __attribute__((ext_vector_type(4))) float f32x4;

__device__ __forceinline__ float bf2f(unsigned short u) {
  union { unsigned int i; float f; } v; v.i = ((unsigned int)u) << 16; return v.f;
}
__device__ __forceinline__ unsigned short f2bf(float f) {
  union { float f; unsigned int i; } v; v.f = f;
  unsigned int u = v.i;
  return (unsigned short)((u + 0x7fffu + ((u >> 16) & 1u)) >> 16);
}

#define B_SZ 2
#define T_SEQ 2048
#define NH 16
#define DH 128
#define ROPE_R 32
#define SCALE_Q 0.08838834764831845f

// Load 8 consecutive elements as bf16 fragment; F=true -> source is fp32.
template <bool F>
__device__ __forceinline__ short8 ld8(const void* base, size_t idx) {
  if constexpr (F) {
    const float* p = (const float*)base + idx;
    f32x4 a = *(const f32x4*)p;
    f32x4 b = *(const f32x4*)(p + 4);
    short8 r;
    r[0] = (short)f2bf(a[0]); r[1] = (short)f2bf(a[1]);
    r[2] = (short)f2bf(a[2]); r[3] = (short)f2bf(a[3]);
    r[4] = (short)f2bf(b[0]); r[5] = (short)f2bf(b[1]);
    r[6] = (short)f2bf(b[2]); r[7] = (short)f2bf(b[3]);
    return r;
  } else {
    return *(const short8*)((const unsigned short*)base + idx);
  }
}

// ---------------------------------------------------------------------------
// Fallback GEMM (previous session's proven kernel). Used only if workspace is
// too small for the bf16-converted-operand fast path.
// ---------------------------------------------------------------------------
template <bool AF, bool BF, bool C32>
__global__ __launch_bounds__(256) void gemm_bt(
    const void* __restrict__ Ap, const void* __restrict__ Bp,
    void* __restrict__ Cp, int M, int N, int K) {
  __shared__ unsigned short Al[128][40];
  __shared__ unsigned short Bl[128][40];
  const int tid = threadIdx.x;
  const int lane = tid & 63, w = tid >> 6;
  const int wm = w >> 1, wn = w & 1;
  const int quad = lane >> 4, l16 = lane & 15;
  const int m0 = blockIdx.y * 128, n0 = blockIdx.x * 128;
  f32x4 acc[4][4];
#pragma unroll
  for (int i = 0; i < 4; ++i)
#pragma unroll
    for (int j = 0; j < 4; ++j)
#pragma unroll
      for (int r = 0; r < 4; ++r) acc[i][j][r] = 0.f;

  for (int k0 = 0; k0 < K; k0 += 32) {
    __syncthreads();
#pragma unroll
    for (int p = 0; p < 2; ++p) {
      int v = tid + p * 256;
      int row = v >> 2, kc = (v & 3) * 8;
      *(short8*)&Al[row][kc] = ld8<AF>(Ap, (size_t)(m0 + row) * K + k0 + kc);
      *(short8*)&Bl[row][kc] = ld8<BF>(Bp, (size_t)(n0 + row) * K + k0 + kc);
    }
    __syncthreads();
    short8 a[4];
#pragma unroll
    for (int i = 0; i < 4; ++i)
      a[i] = *(const short8*)&Al[wm * 64 + i * 16 + l16][quad * 8];
#pragma unroll
    for (int j = 0; j < 4; ++j) {
      short8 b = *(const short8*)&Bl[wn * 64 + j * 16 + l16][quad * 8];
#pragma unroll
      for (int i = 0; i < 4; ++i)
        acc[i][j] = __builtin_amdgcn_mfma_f32_16x16x32_bf16(a[i], b, acc[i][j], 0, 0, 0);
    }
  }
#pragma unroll
  for (int i = 0; i < 4; ++i)
#pragma unroll
    for (int j = 0; j < 4; ++j) {
      int row = m0 + wm * 64 + i * 16 + quad * 4;
      int col = n0 + wn * 64 + j * 16 + l16;
#pragma unroll
      for (int r = 0; r < 4; ++r) {
        if constexpr (C32)
          ((float*)Cp)[(size_t)(row + r) * N + col] = acc[i][j][r];
        else
          ((unsigned short*)Cp)[(size_t)(row + r) * N + col] = f2bf(acc[i][j][r]);
      }
    }
}

// ---------------------------------------------------------------------------
// Fast GEMM: m97 structure. Both operands bf16 in global memory; staging via
// global_load_lds dwordx4 (direct HBM->LDS DMA). Linear LDS [rows][32].
// LDA: row stride of A in elements (A may be a column-slice of a wider
// buffer, e.g. the merged qs|kvs|gates activation).
// ---------------------------------------------------------------------------
__device__ __forceinline__ void gload_lds16(const unsigned short* g, unsigned short* l) {
  __builtin_amdgcn_global_load_lds(
      (const __attribute__((address_space(1))) void*)g,
      (__attribute__((address_space(3))) void*)l, 16, 0, 0);
}

template <int BN, bool C32>
__global__ __launch_bounds__(256) void gemm_lds(
    const unsigned short* __restrict__ A, const unsigned short* __restrict__ Bw,
    void* __restrict__ Cp, int M, int N, int K, int LDA) {
  __shared__ unsigned short Al[128][32];
  __shared__ unsigned short Bl[BN][32];
  const int tid = threadIdx.x;
  const int lane = tid & 63, w = tid >> 6;
  const int wm = w >> 1, wn = w & 1;
  const int quad = lane >> 4, l16 = lane & 15;
  const int m0 = blockIdx.y * 128, n0 = blockIdx.x * BN;
  constexpr int NJ = BN / 32;
  f32x4 acc[4][NJ];
#pragma unroll
  for (int i = 0; i < 4; ++i)
#pragma unroll
    for (int j = 0; j < NJ; ++j)
#pragma unroll
      for (int r = 0; r < 4; ++r) acc[i][j][r] = 0.f;

  for (int k0 = 0; k0 < K; k0 += 32) {
    __syncthreads();
#pragma unroll
    for (int p = 0; p < 2; ++p) {
      int c = w * 128 + p * 64 + lane;
      gload_lds16(A + (size_t)(m0 + (c >> 2)) * LDA + k0 + (c & 3) * 8,
                  &Al[0][0] + (size_t)(w * 128 + p * 64) * 8);
    }
#pragma unroll
    for (int p = 0; p < BN / 64; ++p) {
      int c = w * BN + p * 64 + lane;
      gload_lds16(Bw + (size_t)(n0 + (c >> 2)) * K + k0 + (c & 3) * 8,
                  &Bl[0][0] + (size_t)(w * BN + p * 64) * 8);
    }
    __syncthreads();
    short8 a[4], b[NJ];
#pragma unroll
    for (int i = 0; i < 4; ++i)
      a[i] = *(const short8*)&Al[wm * 64 + i * 16 + l16][quad * 8];
#pragma unroll
    for (int j = 0; j < NJ; ++j)
      b[j] = *(const short8*)&Bl[wn * (BN / 2) + j * 16 + l16][quad * 8];
#pragma unroll
    for (int j = 0; j < NJ; ++j)
#pragma unroll
      for (int i = 0; i < 4; ++i)
        acc[i][j] = __builtin_amdgcn_mfma_f32_16x16x32_bf16(a[i], b[j], acc[i][j], 0, 0, 0);
  }
#pragma unroll
  for (int i = 0; i < 4; ++i)
#pragma unroll
    for (int j = 0; j < NJ; ++j) {
      int row = m0 + wm * 64 + i * 16 + quad * 4;
      int col = n0 + wn * (BN / 2) + j * 16 + l16;
#pragma unroll
      for (int r = 0; r < 4; ++r) {
        if constexpr (C32)
          ((float*)Cp)[(size_t)(row + r) * N + col] = acc[i][j][r];
        else
          ((unsigned short*)Cp)[(size_t)(row + r) * N + col] = f2bf(acc[i][j][r]);
      }
    }
}

// ---------------------------------------------------------------------------
// One-shot fp32 -> bf16 conversion of x + all weights (8 segments, 1 launch).
// ---------------------------------------------------------------------------
struct CvtArgs {
  const float* src[8];
  unsigned short* dst[8];
  long long n4[8];
};

__global__ __launch_bounds__(256) void cvt_multi(CvtArgs a, long long total4) {
  for (long long g = (long long)blockIdx.x * 256 + threadIdx.x; g < total4;
       g += (long long)gridDim.x * 256) {
    long long r = g;
    int s = 0;
    while (r >= a.n4[s]) { r -= a.n4[s]; ++s; }
    f32x4 v = ((const f32x4*)a.src[s])[r];
    sh4 o;
    o[0] = (short)f2bf(v[0]); o[1] = (short)f2bf(v[1]);
    o[2] = (short)f2bf(v[2]); o[3] = (short)f2bf(v[3]);
    ((sh4*)a.dst[s])[r] = o;
  }
}

// ---------------------------------------------------------------------------
// In-place RMS norm of an N-wide slice of rows with row stride LD elements.
// ---------------------------------------------------------------------------
__global__ __launch_bounds__(256) void rms_norm_ip(
    unsigned short* __restrict__ x, const float* __restrict__ w, int N, int LD) {
  unsigned short* row = x + (size_t)blockIdx.x * LD;
  float vals[8];
  int cnt = 0;
  float ss = 0.f;
  for (int j = threadIdx.x; j < N; j += 256) {
    float v = bf2f(row[j]);
    vals[cnt++] = v;
    ss += v * v;
  }
#pragma unroll
  for (int d = 1; d < 64; d <<= 1) ss += __shfl_xor(ss, d);
  __shared__ float ws4[4];
  if ((threadIdx.x & 63) == 0) ws4[threadIdx.x >> 6] = ss;
  __syncthreads();
  float tot = ws4[0] + ws4[1] + ws4[2] + ws4[3];
  float scale = rsqrtf(tot / (float)N + 1e-6f);
  cnt = 0;
  for (int j = threadIdx.x; j < N; j += 256)
    row[j] = f2bf(w[j] * vals[cnt++] * scale);
}

// ---------------------------------------------------------------------------
__global__ __launch_bounds__(256) void prep_qk(
    const unsigned short* __restrict__ q_all, const unsigned short* __restrict__ k_all,
    const float* __restrict__ cosb, const float* __restrict__ sinb,
    unsigned short* __restrict__ Q, unsigned short* __restrict__ K) {
  const int bt = blockIdx.x;
  const int b = bt >> 11, t = bt & (T_SEQ - 1);
  const unsigned short* qr = q_all + (size_t)bt * (NH * DH);
  const unsigned short* kr = k_all + (size_t)bt * (NH * DH);
  for (int d = threadIdx.x; d < NH * DH; d += 256) {
    int h = d >> 7, dd = d & 127;
    float qv = bf2f(qr[d]);
    float kv = bf2f(kr[d]);
    if (dd < ROPE_R) {
      float c = cosb[t * ROPE_R + dd];
      float s = sinb[t * ROPE_R + dd];
      float qrot = (dd < 16) ? -bf2f(qr[d + 16]) : bf2f(qr[d - 16]);
      float krot = (dd < 16) ? -bf2f(kr[d + 16]) : bf2f(kr[d - 16]);
      qv = qv * c + qrot * s;
      kv = kv * c + krot * s;
    }
    size_t o = ((size_t)(b * NH + h) * T_SEQ + t) * DH + dd;
    Q[o] = f2bf(qv * SCALE_Q);
    K[o] = f2bf(kv);
  }
}

// ---------------------------------------------------------------------------
// gates may live inside a wider merged activation row: row stride = gstride.
// ---------------------------------------------------------------------------
__global__ __launch_bounds__(256) void prep_vt(
    const unsigned short* __restrict__ v_all, const unsigned short* __restrict__ gates,
    unsigned short* __restrict__ Vt, int gstride) {
  __shared__ unsigned short tile[64][130];
  const int bh = blockIdx.y, b = bh >> 4, h = bh & 15;
  const int t0 = blockIdx.x * 64;
  for (int idx = threadIdx.x; idx < 64 * 128; idx += 256) {
    int tt = idx >> 7, dd = idx & 127;
    size_t rowbase = (size_t)(b * T_SEQ + t0 + tt);
    float v = bf2f(v_all[rowbase * (NH * DH) + h * DH + dd]);
    float g = bf2f(gates[rowbase * (size_t)gstride + h * DH + dd]);
    float sg = g / (1.f + __expf(-g));
    tile[tt][dd] = f2bf(v * sg);
  }
  __syncthreads();
  for (int idx = threadIdx.x; idx < 64 * 128; idx += 256) {
    int dd = idx >> 6, tt = idx & 63;
    Vt[((size_t)bh * DH + dd) * T_SEQ + t0 + tt] = tile[tt][dd];
  }
}

// ---------------------------------------------------------------------------
// Online-softmax update for one 16-row slice of a q-tile vs the staged 64-key
// tile in LDS (round-7 version: best measured). defer-max (T13, THR=8);
// per-lane l_part with epilogue cross-lane reduce.
// ---------------------------------------------------------------------------
__device__ __forceinline__ void attn_update(
    const unsigned short (*Kl)[132], const unsigned short (*Vl)[68],
    unsigned short (*Pw)[96], const short8* qf, int qt, int kb, bool diag,
    int wt, int quad, int l16, f32x4* O, float* m_run, float* l_part) {
  f32x4 sc[4];
  __builtin_amdgcn_s_setprio(1);
#pragma unroll
  for (int jt = 0; jt < 4; ++jt) {
#pragma unroll
    for (int r = 0; r < 4; ++r) sc[jt][r] = 0.f;
#pragma unroll
    for (int kk = 0; kk < 4; ++kk) {
      short8 kf = *(const short8*)&Kl[jt * 16 + l16][kk * 32 + quad * 8];
      sc[jt] = __builtin_amdgcn_mfma_f32_16x16x32_bf16(qf[kk], kf, sc[jt], 0, 0, 0);
    }
  }
  __builtin_amdgcn_s_setprio(0);
  if (diag) {
#pragma unroll
    for (int jt = 0; jt < 4; ++jt) {
      int key = kb + jt * 16 + l16;
#pragma unroll
      for (int r = 0; r < 4; ++r) {
        int row = qt * 64 + wt * 16 + quad * 4 + r;
        if (key > row) sc[jt][r] = -1e30f;
      }
    }
  }
  float pmax[4];
#pragma unroll
  for (int r = 0; r < 4; ++r)
    pmax[r] = fmaxf(fmaxf(sc[0][r], sc[1][r]), fmaxf(sc[2][r], sc[3][r]));
  bool near = (pmax[0] <= m_run[0] + 8.f) & (pmax[1] <= m_run[1] + 8.f) &
              (pmax[2] <= m_run[2] + 8.f) & (pmax[3] <= m_run[3] + 8.f);
  if (!__all((int)near)) {
    float alpha[4];
#pragma unroll
    for (int r = 0; r < 4; ++r) {
      float mx = pmax[r];
      mx = fmaxf(mx, __shfl_xor(mx, 1)); mx = fmaxf(mx, __shfl_xor(mx, 2));
      mx = fmaxf(mx, __shfl_xor(mx, 4)); mx = fmaxf(mx, __shfl_xor(mx, 8));
      float mnew = fmaxf(m_run[r], mx);
      alpha[r] = __expf(m_run[r] - mnew);
      m_run[r] = mnew;
    }
#pragma unroll
    for (int r = 0; r < 4; ++r) l_part[r] *= alpha[r];
#pragma unroll
    for (int jn = 0; jn < 8; ++jn)
#pragma unroll
      for (int r = 0; r < 4; ++r) O[jn][r] *= alpha[r];
  }
#pragma unroll
  for (int jt = 0; jt < 4; ++jt)
#pragma unroll
    for (int r = 0; r < 4; ++r) {
      float p = __expf(sc[jt][r] - m_run[r]);
      sc[jt][r] = p;
      l_part[r] += p;
    }
  // P: C-layout -> wave-private LDS -> A-layout (no sync needed)
#pragma unroll
  for (int jt = 0; jt < 4; ++jt)
#pragma unroll
    for (int r = 0; r < 4; ++r)
      Pw[quad * 4 + r][jt * 16 + l16] = f2bf(sc[jt][r]);
  short8 pa[2];
#pragma unroll
  for (int kk = 0; kk < 2; ++kk)
    pa[kk] = *(const short8*)&Pw[l16][kk * 32 + quad * 8];
  __builtin_amdgcn_s_setprio(1);
#pragma unroll
  for (int jn = 0; jn < 8; ++jn) {
#pragma unroll
    for (int kk = 0; kk < 2; ++kk) {
      short8 vf = *(const short8*)&Vl[jn * 16 + l16][kk * 32 + quad * 8];
      O[jn] = __builtin_amdgcn_mfma_f32_16x16x32_bf16(pa[kk], vf, O[jn], 0, 0, 0);
    }
  }
  __builtin_amdgcn_s_setprio(0);
}

// ---------------------------------------------------------------------------
// Causal flash attention (round-7 version, best measured: 270 us).
// LDS K/V staging + 8-wave A/B tile split + paired qa/qb blocks + XCD swizzle
// + defer-max + per-lane l_part. 58.9 KB LDS, 2 blocks/CU.
// ---------------------------------------------------------------------------
__global__ __launch_bounds__(512, 2) void flash_attn(
    const unsigned short* __restrict__ Q, const unsigned short* __restrict__ K,
    const unsigned short* __restrict__ Vt, unsigned short* __restrict__ Out) {
  __shared__ unsigned short Kl[64][132];
  __shared__ unsigned short Vl[128][68];
  __shared__ unsigned short P_lds[8][16][96];
  const int l = blockIdx.x;
  const int s = l & 7, qq = l >> 3;
  const int bh = s + 8 * (qq >> 4);
  const int qp = qq & 15;
  const int qa = qp, qb = 31 - qp;
  const int b = bh >> 4, h = bh & 15;
  const int tid = threadIdx.x;
  const int lane = tid & 63, w = tid >> 6;  // w in 0..7
  const int wt = w & 3;                     // 16-row quarter within the tile
  const bool isB = w >= 4;                  // tile ownership
  const int myq = isB ? qb : qa;
  const int quad = lane >> 4, l16 = lane & 15;
  const unsigned short* Qb = Q + (size_t)bh * T_SEQ * DH;
  const unsigned short* Kb = K + (size_t)bh * T_SEQ * DH;
  const unsigned short* Vb = Vt + (size_t)bh * DH * T_SEQ;

  short8 qf[4];
  const int qrow = myq * 64 + wt * 16 + l16;
#pragma unroll
  for (int kk = 0; kk < 4; ++kk)
    qf[kk] = *(const short8*)&Qb[(size_t)qrow * DH + kk * 32 + quad * 8];

  f32x4 O[8];
  float m_run[4], l_part[4];
#pragma unroll
  for (int jn = 0; jn < 8; ++jn)
#pragma unroll
    for (int r = 0; r < 4; ++r) O[jn][r] = 0.f;
#pragma unroll
  for (int r = 0; r < 4; ++r) { m_run[r] = -1e30f; l_part[r] = 0.f; }

  short8 krg[2], vrg[2];
#pragma unroll
  for (int p = 0; p < 2; ++p) {
    int id = tid + p * 512;
    krg[p] = *(const short8*)&Kb[(size_t)(id >> 4) * DH + (id & 15) * 8];
    vrg[p] = *(const short8*)&Vb[(size_t)(id >> 3) * T_SEQ + (id & 7) * 8];
  }
#pragma unroll
  for (int p = 0; p < 2; ++p) {
    int id = tid + p * 512;
    *(short8*)&Kl[id >> 4][(id & 15) * 8] = krg[p];
    *(short8*)&Vl[id >> 3][(id & 7) * 8] = vrg[p];
  }
  __syncthreads();

  const int last = qb;
  for (int kt = 0; kt <= last; ++kt) {
    const int kb = kt * 64;
    if (kt < last) {  // prefetch next tile into registers (overlaps compute)
      const int nb = kb + 64;
#pragma unroll
      for (int p = 0; p < 2; ++p) {
        int id = tid + p * 512;
        krg[p] = *(const short8*)&Kb[(size_t)(nb + (id >> 4)) * DH + (id & 15) * 8];
        vrg[p] = *(const short8*)&Vb[(size_t)(id >> 3) * T_SEQ + nb + (id & 7) * 8];
      }
    }
    if (isB || kt <= qa)
      attn_update(Kl, Vl, P_lds[w], qf, myq, kb, kt == (isB ? last : qa),
                  wt, quad, l16, O, m_run, l_part);
    if (kt < last) {
      __syncthreads();  // all waves done reading Kl/Vl
#pragma unroll
      for (int p = 0; p < 2; ++p) {
        int id = tid + p * 512;
        *(short8*)&Kl[id >> 4][(id & 15) * 8] = krg[p];
        *(short8*)&Vl[id >> 3][(id & 7) * 8] = vrg[p];
      }
      __syncthreads();  // staging visible
    }
  }

  float l_run[4];
#pragma unroll
  for (int r = 0; r < 4; ++r) {
    float ssum = l_part[r];
    ssum += __shfl_xor(ssum, 1); ssum += __shfl_xor(ssum, 2);
    ssum += __shfl_xor(ssum, 4); ssum += __shfl_xor(ssum, 8);
    l_run[r] = ssum;
  }
#pragma unroll
  for (int jn = 0; jn < 8; ++jn)
#pragma unroll
    for (int r = 0; r < 4; ++r) {
      int rr = myq * 64 + wt * 16 + quad * 4 + r;
      Out[((size_t)(b * T_SEQ) + rr) * (NH * DH) + h * DH + jn * 16 + l16] =
          f2bf(O[jn][r] / l_run[r]);
    }
}

// ---------------------------------------------------------------------------
// Workspace plan (fast path). qs|kvs|gates and Wq_s_b|Wkv_s_b|Wg_p_b are laid
// out contiguously, so the first THREE x-GEMMs merge into ONE N=3328 GEMM
// writing merged rows [qs(768) | kvs(512) | gates(2048)], stride 3328.
//   merged @0 (27.26M) ; v_all/Qb @27,262,976 ; Vt @44,040,192 ;
//   Kb @60,817,408 ; xb @77,594,624 (dead after merged GEMM -> reused as
//   k_all) ; bf16 weights @94,371,840.. ; omid @0 (written after merged dead)
// ---------------------------------------------------------------------------
extern "C" void kernel_launch(void* const* d_in, const int* in_sizes, int n_in,
                              void* d_out, int out_size, void* d_ws, size_t ws_size,
                              hipStream_t stream) {
  const void*  x     = d_in[0];
  const float* cosb  = (const float*)d_in[1];
  const float* sinb  = (const float*)d_in[2];
  const void*  Wq_s  = d_in[3];
  const float* qs_w  = (const float*)d_in[4];
  const void*  Wkv_s = d_in[5];
  const float* kvs_w = (const float*)d_in[6];
  const void*  Wq_p  = d_in[7];
  const float* Wkv_p = (const float*)d_in[8];
  const void*  Wg_p  = d_in[9];
  const void*  Wo_p  = d_in[10];
  const float* o_w   = (const float*)d_in[11];
  const void*  Wo_s  = d_in[12];
  (void)in_sizes; (void)n_in; (void)out_size;

  const int M = B_SZ * T_SEQ;  // 4096
  char* ws = (char*)d_ws;
  unsigned short* qs    = (unsigned short*)(ws + 0);
  unsigned short* omid  = qs;
  unsigned short* kvs   = (unsigned short*)(ws + 6291456);
  unsigned short* gates = (unsigned short*)(ws + 10485760);
  unsigned short* k_all = gates;
  unsigned short* v_all = (unsigned short*)(ws + 27262976);
  unsigned short* Qb    = v_all;
  unsigned short* Vt    = (unsigned short*)(ws + 44040192);
  unsigned short* Kb    = (unsigned short*)(ws + 60817408);
  unsigned short* q_all = (unsigned short*)d_out;
  unsigned short* attn  = (unsigned short*)d_out;

  dim3 blk(256);
  dim3 blk512(512);
  const size_t FAST_WS_NEEDED = 119537664;  // 114 MiB

  if (ws_size >= FAST_WS_NEEDED) {
    unsigned short* xb     = (unsigned short*)(ws + 77594624);
    unsigned short* Wq_s_b = (unsigned short*)(ws + 94371840);
    unsigned short* Wkv_s_b= (unsigned short*)(ws + 97517568);
    unsigned short* Wg_p_b = (unsigned short*)(ws + 99614720);
    unsigned short* Wq_p_b = (unsigned short*)(ws + 108003328);
    unsigned short* Wkv_p_b= (unsigned short*)(ws + 111149056);
    unsigned short* Wo_p_b = (unsigned short*)(ws + 115343360);
    unsigned short* Wo_s_b = (unsigned short*)(ws + 117440512);
    unsigned short* merged = (unsigned short*)(ws + 0);   // 4096 x 3328
    unsigned short* k_new  = xb;  // xb dead after merged GEMM

    CvtArgs ca;
    ca.src[0] = (const float*)x;    ca.dst[0] = xb;      ca.n4[0] = 2097152;
    ca.src[1] = (const float*)Wq_s; ca.dst[1] = Wq_s_b;  ca.n4[1] = 393216;
    ca.src[2] = (const float*)Wkv_s;ca.dst[2] = Wkv_s_b; ca.n4[2] = 262144;
    ca.src[3] = (const float*)Wg_p; ca.dst[3] = Wg_p_b;  ca.n4[3] = 1048576;
    ca.src[4] = (const float*)Wq_p; ca.dst[4] = Wq_p_b;  ca.n4[4] = 393216;
    ca.src[5] = Wkv_p;              ca.dst[5] = Wkv_p_b; ca.n4[5] = 524288;
    ca.src[6] = (const float*)Wo_p; ca.dst[6] = Wo_p_b;  ca.n4[6] = 262144;
    ca.src[7] = (const float*)Wo_s; ca.dst[7] = Wo_s_b;  ca.n4[7] = 262144;
    long long total4 = 5242880;
    cvt_multi<<<dim3(2048), blk, 0, stream>>>(ca, total4);

    // merged x-GEMM: [qs | kvs | gates] = x @ [Wq_s;Wkv_s;Wg_p]^T  (N=3328)
    gemm_lds<128, false><<<dim3(3328 / 128, M / 128), blk, 0, stream>>>(
        xb, Wq_s_b, merged, M, 3328, 2048, 2048);
    rms_norm_ip<<<M, blk, 0, stream>>>(merged, qs_w, 768, 3328);
    rms_norm_ip<<<M, blk, 0, stream>>>(merged + 768, kvs_w, 512, 3328);
    gemm_lds<128, false><<<dim3(2048 / 128, M / 128), blk, 0, stream>>>(
        merged, Wq_p_b, q_all, M, 2048, 768, 3328);
    gemm_lds<128, false><<<dim3(2048 / 128, M / 128), blk, 0, stream>>>(
        merged + 768, Wkv_p_b + (size_t)2048 * 512, v_all, M, 2048, 512, 3328);
    prep_vt<<<dim3(T_SEQ / 64, B_SZ * NH), blk, 0, stream>>>(
        v_all, merged + 1280, Vt, 3328);
    gemm_lds<128, false><<<dim3(2048 / 128, M / 128), blk, 0, stream>>>(
        merged + 768, Wkv_p_b, k_new, M, 2048, 512, 3328);
    prep_qk<<<M, blk, 0, stream>>>(q_all, k_new, cosb, sinb, Qb, Kb);
    flash_attn<<<dim3(512), blk512, 0, stream>>>(Qb, Kb, Vt, attn);
    gemm_lds<64, false><<<dim3(512 / 64, M / 128), blk, 0, stream>>>(
        attn, Wo_p_b, omid, M, 512, 2048, 2048);
    rms_norm_ip<<<M, blk, 0, stream>>>(omid, o_w, 512, 512);
    gemm_lds<128, true><<<dim3(2048 / 128, M / 128), blk, 0, stream>>>(
        omid, Wo_s_b, d_out, M, 2048, 512, 512);
  } else {
    gemm_bt<true, true, false><<<dim3(768 / 128, M / 128), blk, 0, stream>>>(x, Wq_s, qs, M, 768, 2048);
    gemm_bt<true, true, false><<<dim3(512 / 128, M / 128), blk, 0, stream>>>(x, Wkv_s, kvs, M, 512, 2048);
    gemm_bt<true, true, false><<<dim3(2048 / 128, M / 128), blk, 0, stream>>>(x, Wg_p, gates, M, 2048, 2048);
    rms_norm_ip<<<M, blk, 0, stream>>>(qs, qs_w, 768, 768);
    rms_norm_ip<<<M, blk, 0, stream>>>(kvs, kvs_w, 512, 512);
    gemm_bt<false, true, false><<<dim3(2048 / 128, M / 128), blk, 0, stream>>>(qs, Wq_p, q_all, M, 2048, 768);
    gemm_bt<false, true, false><<<dim3(2048 / 128, M / 128), blk, 0, stream>>>(
        kvs, Wkv_p + (size_t)2048 * 512, v_all, M, 2048, 512);
    prep_vt<<<dim3(T_SEQ / 64, B_SZ * NH), blk, 0, stream>>>(v_all, gates, Vt, 2048);
    gemm_bt<false, true, false><<<dim3(2048 / 128, M / 128), blk, 0, stream>>>(kvs, Wkv_p, k_all, M, 2048, 512);
    prep_qk<<<M, blk, 0, stream>>>(q_all, k_all, cosb, sinb, Qb, Kb);
    flash_attn<<<dim3(512), blk512, 0, stream>>>(Qb, Kb, Vt, attn);
    gemm_bt<false, true, false><<<dim3(512 / 128, M / 128), blk, 0, stream>>>(attn, Wo_p, omid, M, 512, 2048);
    rms_norm_ip<<<M, blk, 0, stream>>>(omid, o_w, 512, 512);
    gemm_bt<false, true, true><<<dim3(2048 / 128, M / 128), blk, 0, stream>>>(omid, Wo_s, d_out, M, 2048, 512);
  }
}

// Round 11
// 661.356 us; speedup vs baseline: 1.1010x; 1.0106x over previous
//
#include <hip/hip_runtime.h>
#include <stdint.h>

typedef __attribute__((ext_vector_type(8))) short short8;
typedef __attribute__((ext_vector_type(4))) short sh4;
typedef __attribute__((ext_vector_type(4))) float f32x4;

__device__ __forceinline__ float bf2f(unsigned short u) {
  union { unsigned int i; float f; } v; v.i = ((unsigned int)u) << 16; return v.f;
}
__device__ __forceinline__ unsigned short f2bf(float f) {
  union { float f; unsigned int i; } v; v.f = f;
  unsigned int u = v.i;
  return (unsigned short)((u + 0x7fffu + ((u >> 16) & 1u)) >> 16);
}

#define B_SZ 2
#define T_SEQ 2048
#define NH 16
#define DH 128
#define ROPE_R 32
#define SCALE_Q 0.08838834764831845f

// Load 8 consecutive elements as bf16 fragment; F=true -> source is fp32.
template <bool F>
__device__ __forceinline__ short8 ld8(const void* base, size_t idx) {
  if constexpr (F) {
    const float* p = (const float*)base + idx;
    f32x4 a = *(const f32x4*)p;
    f32x4 b = *(const f32x4*)(p + 4);
    short8 r;
    r[0] = (short)f2bf(a[0]); r[1] = (short)f2bf(a[1]);
    r[2] = (short)f2bf(a[2]); r[3] = (short)f2bf(a[3]);
    r[4] = (short)f2bf(b[0]); r[5] = (short)f2bf(b[1]);
    r[6] = (short)f2bf(b[2]); r[7] = (short)f2bf(b[3]);
    return r;
  } else {
    return *(const short8*)((const unsigned short*)base + idx);
  }
}

// ---------------------------------------------------------------------------
// Fallback GEMM (previous session's proven kernel). Used only if workspace is
// too small for the bf16-converted-operand fast path.
// ---------------------------------------------------------------------------
template <bool AF, bool BF, bool C32>
__global__ __launch_bounds__(256) void gemm_bt(
    const void* __restrict__ Ap, const void* __restrict__ Bp,
    void* __restrict__ Cp, int M, int N, int K) {
  __shared__ unsigned short Al[128][40];
  __shared__ unsigned short Bl[128][40];
  const int tid = threadIdx.x;
  const int lane = tid & 63, w = tid >> 6;
  const int wm = w >> 1, wn = w & 1;
  const int quad = lane >> 4, l16 = lane & 15;
  const int m0 = blockIdx.y * 128, n0 = blockIdx.x * 128;
  f32x4 acc[4][4];
#pragma unroll
  for (int i = 0; i < 4; ++i)
#pragma unroll
    for (int j = 0; j < 4; ++j)
#pragma unroll
      for (int r = 0; r < 4; ++r) acc[i][j][r] = 0.f;

  for (int k0 = 0; k0 < K; k0 += 32) {
    __syncthreads();
#pragma unroll
    for (int p = 0; p < 2; ++p) {
      int v = tid + p * 256;
      int row = v >> 2, kc = (v & 3) * 8;
      *(short8*)&Al[row][kc] = ld8<AF>(Ap, (size_t)(m0 + row) * K + k0 + kc);
      *(short8*)&Bl[row][kc] = ld8<BF>(Bp, (size_t)(n0 + row) * K + k0 + kc);
    }
    __syncthreads();
    short8 a[4];
#pragma unroll
    for (int i = 0; i < 4; ++i)
      a[i] = *(const short8*)&Al[wm * 64 + i * 16 + l16][quad * 8];
#pragma unroll
    for (int j = 0; j < 4; ++j) {
      short8 b = *(const short8*)&Bl[wn * 64 + j * 16 + l16][quad * 8];
#pragma unroll
      for (int i = 0; i < 4; ++i)
        acc[i][j] = __builtin_amdgcn_mfma_f32_16x16x32_bf16(a[i], b, acc[i][j], 0, 0, 0);
    }
  }
#pragma unroll
  for (int i = 0; i < 4; ++i)
#pragma unroll
    for (int j = 0; j < 4; ++j) {
      int row = m0 + wm * 64 + i * 16 + quad * 4;
      int col = n0 + wn * 64 + j * 16 + l16;
#pragma unroll
      for (int r = 0; r < 4; ++r) {
        if constexpr (C32)
          ((float*)Cp)[(size_t)(row + r) * N + col] = acc[i][j][r];
        else
          ((unsigned short*)Cp)[(size_t)(row + r) * N + col] = f2bf(acc[i][j][r]);
      }
    }
}

// ---------------------------------------------------------------------------
// Fast GEMM: m97 structure. Both operands bf16 in global memory; staging via
// global_load_lds dwordx4 (direct HBM->LDS DMA). Linear LDS [rows][32].
// LDA: row stride of A in elements (A may be a column-slice of a wider
// buffer, e.g. the merged qs|kvs|gates activation).
// ---------------------------------------------------------------------------
__device__ __forceinline__ void gload_lds16(const unsigned short* g, unsigned short* l) {
  __builtin_amdgcn_global_load_lds(
      (const __attribute__((address_space(1))) void*)g,
      (__attribute__((address_space(3))) void*)l, 16, 0, 0);
}

template <int BN, bool C32>
__global__ __launch_bounds__(256) void gemm_lds(
    const unsigned short* __restrict__ A, const unsigned short* __restrict__ Bw,
    void* __restrict__ Cp, int M, int N, int K, int LDA) {
  __shared__ unsigned short Al[128][32];
  __shared__ unsigned short Bl[BN][32];
  const int tid = threadIdx.x;
  const int lane = tid & 63, w = tid >> 6;
  const int wm = w >> 1, wn = w & 1;
  const int quad = lane >> 4, l16 = lane & 15;
  const int m0 = blockIdx.y * 128, n0 = blockIdx.x * BN;
  constexpr int NJ = BN / 32;
  f32x4 acc[4][NJ];
#pragma unroll
  for (int i = 0; i < 4; ++i)
#pragma unroll
    for (int j = 0; j < NJ; ++j)
#pragma unroll
      for (int r = 0; r < 4; ++r) acc[i][j][r] = 0.f;

  for (int k0 = 0; k0 < K; k0 += 32) {
    __syncthreads();
#pragma unroll
    for (int p = 0; p < 2; ++p) {
      int c = w * 128 + p * 64 + lane;
      gload_lds16(A + (size_t)(m0 + (c >> 2)) * LDA + k0 + (c & 3) * 8,
                  &Al[0][0] + (size_t)(w * 128 + p * 64) * 8);
    }
#pragma unroll
    for (int p = 0; p < BN / 64; ++p) {
      int c = w * BN + p * 64 + lane;
      gload_lds16(Bw + (size_t)(n0 + (c >> 2)) * K + k0 + (c & 3) * 8,
                  &Bl[0][0] + (size_t)(w * BN + p * 64) * 8);
    }
    __syncthreads();
    short8 a[4], b[NJ];
#pragma unroll
    for (int i = 0; i < 4; ++i)
      a[i] = *(const short8*)&Al[wm * 64 + i * 16 + l16][quad * 8];
#pragma unroll
    for (int j = 0; j < NJ; ++j)
      b[j] = *(const short8*)&Bl[wn * (BN / 2) + j * 16 + l16][quad * 8];
#pragma unroll
    for (int j = 0; j < NJ; ++j)
#pragma unroll
      for (int i = 0; i < 4; ++i)
        acc[i][j] = __builtin_amdgcn_mfma_f32_16x16x32_bf16(a[i], b[j], acc[i][j], 0, 0, 0);
  }
#pragma unroll
  for (int i = 0; i < 4; ++i)
#pragma unroll
    for (int j = 0; j < NJ; ++j) {
      int row = m0 + wm * 64 + i * 16 + quad * 4;
      int col = n0 + wn * (BN / 2) + j * 16 + l16;
#pragma unroll
      for (int r = 0; r < 4; ++r) {
        if constexpr (C32)
          ((float*)Cp)[(size_t)(row + r) * N + col] = acc[i][j][r];
        else
          ((unsigned short*)Cp)[(size_t)(row + r) * N + col] = f2bf(acc[i][j][r]);
      }
    }
}

// ---------------------------------------------------------------------------
// One-shot fp32 -> bf16 conversion of x + all weights (8 segments, 1 launch).
// ---------------------------------------------------------------------------
struct CvtArgs {
  const float* src[8];
  unsigned short* dst[8];
  long long n4[8];
};

__global__ __launch_bounds__(256) void cvt_multi(CvtArgs a, long long total4) {
  for (long long g = (long long)blockIdx.x * 256 + threadIdx.x; g < total4;
       g += (long long)gridDim.x * 256) {
    long long r = g;
    int s = 0;
    while (r >= a.n4[s]) { r -= a.n4[s]; ++s; }
    f32x4 v = ((const f32x4*)a.src[s])[r];
    sh4 o;
    o[0] = (short)f2bf(v[0]); o[1] = (short)f2bf(v[1]);
    o[2] = (short)f2bf(v[2]); o[3] = (short)f2bf(v[3]);
    ((sh4*)a.dst[s])[r] = o;
  }
}

// ---------------------------------------------------------------------------
// In-place RMS norm of an N-wide slice of rows with row stride LD elements.
// ---------------------------------------------------------------------------
__global__ __launch_bounds__(256) void rms_norm_ip(
    unsigned short* __restrict__ x, const float* __restrict__ w, int N, int LD) {
  unsigned short* row = x + (size_t)blockIdx.x * LD;
  float vals[8];
  int cnt = 0;
  float ss = 0.f;
  for (int j = threadIdx.x; j < N; j += 256) {
    float v = bf2f(row[j]);
    vals[cnt++] = v;
    ss += v * v;
  }
#pragma unroll
  for (int d = 1; d < 64; d <<= 1) ss += __shfl_xor(ss, d);
  __shared__ float ws4[4];
  if ((threadIdx.x & 63) == 0) ws4[threadIdx.x >> 6] = ss;
  __syncthreads();
  float tot = ws4[0] + ws4[1] + ws4[2] + ws4[3];
  float scale = rsqrtf(tot / (float)N + 1e-6f);
  cnt = 0;
  for (int j = threadIdx.x; j < N; j += 256)
    row[j] = f2bf(w[j] * vals[cnt++] * scale);
}

// ---------------------------------------------------------------------------
// Dual RMS norm: grid (M, 2). blockIdx.y==0 -> cols [0,768) with w0;
// blockIdx.y==1 -> cols [768,1280) with w1. One launch replaces two.
// ---------------------------------------------------------------------------
__global__ __launch_bounds__(256) void rms_norm_dual(
    unsigned short* __restrict__ x, const float* __restrict__ w0,
    const float* __restrict__ w1, int LD) {
  const int which = blockIdx.y;
  const int off = which ? 768 : 0;
  const int N = which ? 512 : 768;
  const float* w = which ? w1 : w0;
  unsigned short* row = x + (size_t)blockIdx.x * LD + off;
  float vals[3];
  int cnt = 0;
  float ss = 0.f;
  for (int j = threadIdx.x; j < N; j += 256) {
    float v = bf2f(row[j]);
    vals[cnt++] = v;
    ss += v * v;
  }
#pragma unroll
  for (int d = 1; d < 64; d <<= 1) ss += __shfl_xor(ss, d);
  __shared__ float ws4[4];
  if ((threadIdx.x & 63) == 0) ws4[threadIdx.x >> 6] = ss;
  __syncthreads();
  float tot = ws4[0] + ws4[1] + ws4[2] + ws4[3];
  float scale = rsqrtf(tot / (float)N + 1e-6f);
  cnt = 0;
  for (int j = threadIdx.x; j < N; j += 256)
    row[j] = f2bf(w[j] * vals[cnt++] * scale);
}

// ---------------------------------------------------------------------------
// q_all row stride = qstride; k_all row stride = kstride (k may be the first
// 2048 cols of the merged kv activation, stride 4096).
// ---------------------------------------------------------------------------
__global__ __launch_bounds__(256) void prep_qk(
    const unsigned short* __restrict__ q_all, const unsigned short* __restrict__ k_all,
    const float* __restrict__ cosb, const float* __restrict__ sinb,
    unsigned short* __restrict__ Q, unsigned short* __restrict__ K,
    int qstride, int kstride) {
  const int bt = blockIdx.x;
  const int b = bt >> 11, t = bt & (T_SEQ - 1);
  const unsigned short* qr = q_all + (size_t)bt * qstride;
  const unsigned short* kr = k_all + (size_t)bt * kstride;
  for (int d = threadIdx.x; d < NH * DH; d += 256) {
    int h = d >> 7, dd = d & 127;
    float qv = bf2f(qr[d]);
    float kv = bf2f(kr[d]);
    if (dd < ROPE_R) {
      float c = cosb[t * ROPE_R + dd];
      float s = sinb[t * ROPE_R + dd];
      float qrot = (dd < 16) ? -bf2f(qr[d + 16]) : bf2f(qr[d - 16]);
      float krot = (dd < 16) ? -bf2f(kr[d + 16]) : bf2f(kr[d - 16]);
      qv = qv * c + qrot * s;
      kv = kv * c + krot * s;
    }
    size_t o = ((size_t)(b * NH + h) * T_SEQ + t) * DH + dd;
    Q[o] = f2bf(qv * SCALE_Q);
    K[o] = f2bf(kv);
  }
}

// ---------------------------------------------------------------------------
// v_all row stride = vstride; gates row stride = gstride (both may live in
// wider merged buffers).
// ---------------------------------------------------------------------------
__global__ __launch_bounds__(256) void prep_vt(
    const unsigned short* __restrict__ v_all, const unsigned short* __restrict__ gates,
    unsigned short* __restrict__ Vt, int gstride, int vstride) {
  __shared__ unsigned short tile[64][130];
  const int bh = blockIdx.y, b = bh >> 4, h = bh & 15;
  const int t0 = blockIdx.x * 64;
  for (int idx = threadIdx.x; idx < 64 * 128; idx += 256) {
    int tt = idx >> 7, dd = idx & 127;
    size_t rowbase = (size_t)(b * T_SEQ + t0 + tt);
    float v = bf2f(v_all[rowbase * (size_t)vstride + h * DH + dd]);
    float g = bf2f(gates[rowbase * (size_t)gstride + h * DH + dd]);
    float sg = g / (1.f + __expf(-g));
    tile[tt][dd] = f2bf(v * sg);
  }
  __syncthreads();
  for (int idx = threadIdx.x; idx < 64 * 128; idx += 256) {
    int dd = idx >> 6, tt = idx & 63;
    Vt[((size_t)bh * DH + dd) * T_SEQ + t0 + tt] = tile[tt][dd];
  }
}

// ---------------------------------------------------------------------------
// Online-softmax update for one 16-row slice of a q-tile vs the staged 64-key
// tile in LDS (round-7 version, best measured). defer-max (T13, THR=8);
// per-lane l_part with epilogue cross-lane reduce.
// ---------------------------------------------------------------------------
__device__ __forceinline__ void attn_update(
    const unsigned short (*Kl)[132], const unsigned short (*Vl)[68],
    unsigned short (*Pw)[96], const short8* qf, int qt, int kb, bool diag,
    int wt, int quad, int l16, f32x4* O, float* m_run, float* l_part) {
  f32x4 sc[4];
  __builtin_amdgcn_s_setprio(1);
#pragma unroll
  for (int jt = 0; jt < 4; ++jt) {
#pragma unroll
    for (int r = 0; r < 4; ++r) sc[jt][r] = 0.f;
#pragma unroll
    for (int kk = 0; kk < 4; ++kk) {
      short8 kf = *(const short8*)&Kl[jt * 16 + l16][kk * 32 + quad * 8];
      sc[jt] = __builtin_amdgcn_mfma_f32_16x16x32_bf16(qf[kk], kf, sc[jt], 0, 0, 0);
    }
  }
  __builtin_amdgcn_s_setprio(0);
  if (diag) {
#pragma unroll
    for (int jt = 0; jt < 4; ++jt) {
      int key = kb + jt * 16 + l16;
#pragma unroll
      for (int r = 0; r < 4; ++r) {
        int row = qt * 64 + wt * 16 + quad * 4 + r;
        if (key > row) sc[jt][r] = -1e30f;
      }
    }
  }
  float pmax[4];
#pragma unroll
  for (int r = 0; r < 4; ++r)
    pmax[r] = fmaxf(fmaxf(sc[0][r], sc[1][r]), fmaxf(sc[2][r], sc[3][r]));
  bool near = (pmax[0] <= m_run[0] + 8.f) & (pmax[1] <= m_run[1] + 8.f) &
              (pmax[2] <= m_run[2] + 8.f) & (pmax[3] <= m_run[3] + 8.f);
  if (!__all((int)near)) {
    float alpha[4];
#pragma unroll
    for (int r = 0; r < 4; ++r) {
      float mx = pmax[r];
      mx = fmaxf(mx, __shfl_xor(mx, 1)); mx = fmaxf(mx, __shfl_xor(mx, 2));
      mx = fmaxf(mx, __shfl_xor(mx, 4)); mx = fmaxf(mx, __shfl_xor(mx, 8));
      float mnew = fmaxf(m_run[r], mx);
      alpha[r] = __expf(m_run[r] - mnew);
      m_run[r] = mnew;
    }
#pragma unroll
    for (int r = 0; r < 4; ++r) l_part[r] *= alpha[r];
#pragma unroll
    for (int jn = 0; jn < 8; ++jn)
#pragma unroll
      for (int r = 0; r < 4; ++r) O[jn][r] *= alpha[r];
  }
#pragma unroll
  for (int jt = 0; jt < 4; ++jt)
#pragma unroll
    for (int r = 0; r < 4; ++r) {
      float p = __expf(sc[jt][r] - m_run[r]);
      sc[jt][r] = p;
      l_part[r] += p;
    }
  // P: C-layout -> wave-private LDS -> A-layout (no sync needed)
#pragma unroll
  for (int jt = 0; jt < 4; ++jt)
#pragma unroll
    for (int r = 0; r < 4; ++r)
      Pw[quad * 4 + r][jt * 16 + l16] = f2bf(sc[jt][r]);
  short8 pa[2];
#pragma unroll
  for (int kk = 0; kk < 2; ++kk)
    pa[kk] = *(const short8*)&Pw[l16][kk * 32 + quad * 8];
  __builtin_amdgcn_s_setprio(1);
#pragma unroll
  for (int jn = 0; jn < 8; ++jn) {
#pragma unroll
    for (int kk = 0; kk < 2; ++kk) {
      short8 vf = *(const short8*)&Vl[jn * 16 + l16][kk * 32 + quad * 8];
      O[jn] = __builtin_amdgcn_mfma_f32_16x16x32_bf16(pa[kk], vf, O[jn], 0, 0, 0);
    }
  }
  __builtin_amdgcn_s_setprio(0);
}

// ---------------------------------------------------------------------------
// Causal flash attention (round-7 version, best measured: ~271 us).
// LDS K/V staging + 8-wave A/B tile split + paired qa/qb blocks + XCD swizzle
// + defer-max + per-lane l_part. 58.9 KB LDS, 2 blocks/CU.
// ---------------------------------------------------------------------------
__global__ __launch_bounds__(512, 2) void flash_attn(
    const unsigned short* __restrict__ Q, const unsigned short* __restrict__ K,
    const unsigned short* __restrict__ Vt, unsigned short* __restrict__ Out) {
  __shared__ unsigned short Kl[64][132];
  __shared__ unsigned short Vl[128][68];
  __shared__ unsigned short P_lds[8][16][96];
  const int l = blockIdx.x;
  const int s = l & 7, qq = l >> 3;
  const int bh = s + 8 * (qq >> 4);
  const int qp = qq & 15;
  const int qa = qp, qb = 31 - qp;
  const int b = bh >> 4, h = bh & 15;
  const int tid = threadIdx.x;
  const int lane = tid & 63, w = tid >> 6;  // w in 0..7
  const int wt = w & 3;                     // 16-row quarter within the tile
  const bool isB = w >= 4;                  // tile ownership
  const int myq = isB ? qb : qa;
  const int quad = lane >> 4, l16 = lane & 15;
  const unsigned short* Qb = Q + (size_t)bh * T_SEQ * DH;
  const unsigned short* Kb = K + (size_t)bh * T_SEQ * DH;
  const unsigned short* Vb = Vt + (size_t)bh * DH * T_SEQ;

  short8 qf[4];
  const int qrow = myq * 64 + wt * 16 + l16;
#pragma unroll
  for (int kk = 0; kk < 4; ++kk)
    qf[kk] = *(const short8*)&Qb[(size_t)qrow * DH + kk * 32 + quad * 8];

  f32x4 O[8];
  float m_run[4], l_part[4];
#pragma unroll
  for (int jn = 0; jn < 8; ++jn)
#pragma unroll
    for (int r = 0; r < 4; ++r) O[jn][r] = 0.f;
#pragma unroll
  for (int r = 0; r < 4; ++r) { m_run[r] = -1e30f; l_part[r] = 0.f; }

  short8 krg[2], vrg[2];
#pragma unroll
  for (int p = 0; p < 2; ++p) {
    int id = tid + p * 512;
    krg[p] = *(const short8*)&Kb[(size_t)(id >> 4) * DH + (id & 15) * 8];
    vrg[p] = *(const short8*)&Vb[(size_t)(id >> 3) * T_SEQ + (id & 7) * 8];
  }
#pragma unroll
  for (int p = 0; p < 2; ++p) {
    int id = tid + p * 512;
    *(short8*)&Kl[id >> 4][(id & 15) * 8] = krg[p];
    *(short8*)&Vl[id >> 3][(id & 7) * 8] = vrg[p];
  }
  __syncthreads();

  const int last = qb;
  for (int kt = 0; kt <= last; ++kt) {
    const int kb = kt * 64;
    if (kt < last) {  // prefetch next tile into registers (overlaps compute)
      const int nb = kb + 64;
#pragma unroll
      for (int p = 0; p < 2; ++p) {
        int id = tid + p * 512;
        krg[p] = *(const short8*)&Kb[(size_t)(nb + (id >> 4)) * DH + (id & 15) * 8];
        vrg[p] = *(const short8*)&Vb[(size_t)(id >> 3) * T_SEQ + nb + (id & 7) * 8];
      }
    }
    if (isB || kt <= qa)
      attn_update(Kl, Vl, P_lds[w], qf, myq, kb, kt == (isB ? last : qa),
                  wt, quad, l16, O, m_run, l_part);
    if (kt < last) {
      __syncthreads();  // all waves done reading Kl/Vl
#pragma unroll
      for (int p = 0; p < 2; ++p) {
        int id = tid + p * 512;
        *(short8*)&Kl[id >> 4][(id & 15) * 8] = krg[p];
        *(short8*)&Vl[id >> 3][(id & 7) * 8] = vrg[p];
      }
      __syncthreads();  // staging visible
    }
  }

  float l_run[4];
#pragma unroll
  for (int r = 0; r < 4; ++r) {
    float ssum = l_part[r];
    ssum += __shfl_xor(ssum, 1); ssum += __shfl_xor(ssum, 2);
    ssum += __shfl_xor(ssum, 4); ssum += __shfl_xor(ssum, 8);
    l_run[r] = ssum;
  }
#pragma unroll
  for (int jn = 0; jn < 8; ++jn)
#pragma unroll
    for (int r = 0; r < 4; ++r) {
      int rr = myq * 64 + wt * 16 + quad * 4 + r;
      Out[((size_t)(b * T_SEQ) + rr) * (NH * DH) + h * DH + jn * 16 + l16] =
          f2bf(O[jn][r] / l_run[r]);
    }
}

// ---------------------------------------------------------------------------
// Workspace plan v2 (fast path), FAST_WS_NEEDED unchanged (114 MiB).
// Liveness-audited layout:
//   merged @0            [0, 27.26M)   written: mergedGEMM; read: rms,qGEMM,
//                                      kvGEMM,prep_vt. Dead after prep_vt.
//   kv_all @27.26M       [27.26M,60.82M) written: kvGEMM (k|v, stride 4096);
//                                      read: prep_vt(v), prep_qk(k).
//   Vt     @60.82M       [60.82M,77.59M) written: prep_vt; read: flash.
//   xb     @77.59M       [77.59M,94.37M) written: cvt; read: mergedGEMM.
//   Qb     @77.59M       reuses xb (dead) — written: prep_qk; read: flash.
//   Kb     @0            reuses merged (dead) — written: prep_qk; read: flash.
//   omid   @27.26M       reuses kv_all (dead after prep_qk) — written after
//                                      flash; read: rms, final GEMM.
//   bf16 weights @94.37M..119.5M.
//   d_out: q_all (qGEMM..prep_qk) -> attn (flash..omidGEMM) -> final fp32.
// ---------------------------------------------------------------------------
extern "C" void kernel_launch(void* const* d_in, const int* in_sizes, int n_in,
                              void* d_out, int out_size, void* d_ws, size_t ws_size,
                              hipStream_t stream) {
  const void*  x     = d_in[0];
  const float* cosb  = (const float*)d_in[1];
  const float* sinb  = (const float*)d_in[2];
  const void*  Wq_s  = d_in[3];
  const float* qs_w  = (const float*)d_in[4];
  const void*  Wkv_s = d_in[5];
  const float* kvs_w = (const float*)d_in[6];
  const void*  Wq_p  = d_in[7];
  const float* Wkv_p = (const float*)d_in[8];
  const void*  Wg_p  = d_in[9];
  const void*  Wo_p  = d_in[10];
  const float* o_w   = (const float*)d_in[11];
  const void*  Wo_s  = d_in[12];
  (void)in_sizes; (void)n_in; (void)out_size;

  const int M = B_SZ * T_SEQ;  // 4096
  char* ws = (char*)d_ws;

  dim3 blk(256);
  dim3 blk512(512);
  const size_t FAST_WS_NEEDED = 119537664;  // 114 MiB

  if (ws_size >= FAST_WS_NEEDED) {
    unsigned short* merged = (unsigned short*)(ws + 0);         // 4096 x 3328
    unsigned short* kv_all = (unsigned short*)(ws + 27262976);  // 4096 x 4096
    unsigned short* Vt     = (unsigned short*)(ws + 60817408);
    unsigned short* xb     = (unsigned short*)(ws + 77594624);
    unsigned short* Qb     = xb;                                 // xb dead
    unsigned short* Kb     = (unsigned short*)(ws + 0);          // merged dead
    unsigned short* omid   = (unsigned short*)(ws + 27262976);   // kv dead
    unsigned short* Wq_s_b = (unsigned short*)(ws + 94371840);
    unsigned short* Wkv_s_b= (unsigned short*)(ws + 97517568);
    unsigned short* Wg_p_b = (unsigned short*)(ws + 99614720);
    unsigned short* Wq_p_b = (unsigned short*)(ws + 108003328);
    unsigned short* Wkv_p_b= (unsigned short*)(ws + 111149056);
    unsigned short* Wo_p_b = (unsigned short*)(ws + 115343360);
    unsigned short* Wo_s_b = (unsigned short*)(ws + 117440512);
    unsigned short* q_all  = (unsigned short*)d_out;
    unsigned short* attn   = (unsigned short*)d_out;

    CvtArgs ca;
    ca.src[0] = (const float*)x;    ca.dst[0] = xb;      ca.n4[0] = 2097152;
    ca.src[1] = (const float*)Wq_s; ca.dst[1] = Wq_s_b;  ca.n4[1] = 393216;
    ca.src[2] = (const float*)Wkv_s;ca.dst[2] = Wkv_s_b; ca.n4[2] = 262144;
    ca.src[3] = (const float*)Wg_p; ca.dst[3] = Wg_p_b;  ca.n4[3] = 1048576;
    ca.src[4] = (const float*)Wq_p; ca.dst[4] = Wq_p_b;  ca.n4[4] = 393216;
    ca.src[5] = Wkv_p;              ca.dst[5] = Wkv_p_b; ca.n4[5] = 524288;
    ca.src[6] = (const float*)Wo_p; ca.dst[6] = Wo_p_b;  ca.n4[6] = 262144;
    ca.src[7] = (const float*)Wo_s; ca.dst[7] = Wo_s_b;  ca.n4[7] = 262144;
    long long total4 = 5242880;
    cvt_multi<<<dim3(2048), blk, 0, stream>>>(ca, total4);

    // merged x-GEMM: [qs | kvs | gates] = x @ [Wq_s;Wkv_s;Wg_p]^T  (N=3328)
    gemm_lds<128, false><<<dim3(3328 / 128, M / 128), blk, 0, stream>>>(
        xb, Wq_s_b, merged, M, 3328, 2048, 2048);
    // fused RMS of qs (768) and kvs (512) slices in one launch
    rms_norm_dual<<<dim3(M, 2), blk, 0, stream>>>(merged, qs_w, kvs_w, 3328);
    gemm_lds<128, false><<<dim3(2048 / 128, M / 128), blk, 0, stream>>>(
        merged, Wq_p_b, q_all, M, 2048, 768, 3328);
    // merged kv-GEMM: [k_all | v_all] = kvs @ Wkv_p^T  (N=4096, one launch)
    gemm_lds<128, false><<<dim3(4096 / 128, M / 128), blk, 0, stream>>>(
        merged + 768, Wkv_p_b, kv_all, M, 4096, 512, 3328);
    prep_vt<<<dim3(T_SEQ / 64, B_SZ * NH), blk, 0, stream>>>(
        kv_all + 2048, merged + 1280, Vt, 3328, 4096);
    prep_qk<<<M, blk, 0, stream>>>(q_all, kv_all, cosb, sinb, Qb, Kb, 2048, 4096);
    flash_attn<<<dim3(512), blk512, 0, stream>>>(Qb, Kb, Vt, attn);
    gemm_lds<64, false><<<dim3(512 / 64, M / 128), blk, 0, stream>>>(
        attn, Wo_p_b, omid, M, 512, 2048, 2048);
    rms_norm_ip<<<M, blk, 0, stream>>>(omid, o_w, 512, 512);
    gemm_lds<128, true><<<dim3(2048 / 128, M / 128), blk, 0, stream>>>(
        omid, Wo_s_b, d_out, M, 2048, 512, 512);
  } else {
    // Fallback: pre-merge layout, proven path.
    unsigned short* qs    = (unsigned short*)(ws + 0);
    unsigned short* omid  = qs;
    unsigned short* kvs   = (unsigned short*)(ws + 6291456);
    unsigned short* gates = (unsigned short*)(ws + 10485760);
    unsigned short* k_all = gates;
    unsigned short* v_all = (unsigned short*)(ws + 27262976);
    unsigned short* Qb    = v_all;
    unsigned short* Vt    = (unsigned short*)(ws + 44040192);
    unsigned short* Kb    = (unsigned short*)(ws + 60817408);
    unsigned short* q_all = (unsigned short*)d_out;
    unsigned short* attn  = (unsigned short*)d_out;

    gemm_bt<true, true, false><<<dim3(768 / 128, M / 128), blk, 0, stream>>>(x, Wq_s, qs, M, 768, 2048);
    gemm_bt<true, true, false><<<dim3(512 / 128, M / 128), blk, 0, stream>>>(x, Wkv_s, kvs, M, 512, 2048);
    gemm_bt<true, true, false><<<dim3(2048 / 128, M / 128), blk, 0, stream>>>(x, Wg_p, gates, M, 2048, 2048);
    rms_norm_ip<<<M, blk, 0, stream>>>(qs, qs_w, 768, 768);
    rms_norm_ip<<<M, blk, 0, stream>>>(kvs, kvs_w, 512, 512);
    gemm_bt<false, true, false><<<dim3(2048 / 128, M / 128), blk, 0, stream>>>(qs, Wq_p, q_all, M, 2048, 768);
    gemm_bt<false, true, false><<<dim3(2048 / 128, M / 128), blk, 0, stream>>>(
        kvs, Wkv_p + (size_t)2048 * 512, v_all, M, 2048, 512);
    prep_vt<<<dim3(T_SEQ / 64, B_SZ * NH), blk, 0, stream>>>(v_all, gates, Vt, 2048, 2048);
    gemm_bt<false, true, false><<<dim3(2048 / 128, M / 128), blk, 0, stream>>>(kvs, Wkv_p, k_all, M, 2048, 512);
    prep_qk<<<M, blk, 0, stream>>>(q_all, k_all, cosb, sinb, Qb, Kb, 2048, 2048);
    flash_attn<<<dim3(512), blk512, 0, stream>>>(Qb, Kb, Vt, attn);
    gemm_bt<false, true, false><<<dim3(512 / 128, M / 128), blk, 0, stream>>>(attn, Wo_p, omid, M, 512, 2048);
    rms_norm_ip<<<M, blk, 0, stream>>>(omid, o_w, 512, 512);
    gemm_bt<false, true, true><<<dim3(2048 / 128, M / 128), blk, 0, stream>>>(omid, Wo_s, d_out, M, 2048, 512);
  }
}